// Round 9
// baseline (126.370 us; speedup 1.0000x reference)
//
#include <hip/hip_runtime.h>

#define SQ 2048
#define DM 512
#define NH 8
#define NSPLIT 4

typedef __bf16 bf16x8 __attribute__((ext_vector_type(8)));
typedef float f32x4 __attribute__((ext_vector_type(4)));
typedef unsigned short us8 __attribute__((ext_vector_type(8)));
typedef unsigned short us4 __attribute__((ext_vector_type(4)));

__device__ __forceinline__ unsigned short f2bf(float f) {
    unsigned u = __builtin_bit_cast(unsigned, f);
    u += 0x7fffu + ((u >> 16) & 1u);     // round-to-nearest-even
    return (unsigned short)(u >> 16);
}
__device__ __forceinline__ float bf2f(unsigned short u) {
    return __builtin_bit_cast(float, (unsigned)u << 16);
}

// ---------------------------------------------------------------------------
// Kernel 0: WEIGHT conversions only (emb/K/V conversion fused into qkv_mfma).
// ---------------------------------------------------------------------------
__global__ __launch_bounds__(256) void convert_w(
    const float* __restrict__ Wq,  const float* __restrict__ Wk,  const float* __restrict__ Wv,
    const float* __restrict__ Wo,
    unsigned short* __restrict__ Wt,
    unsigned short* __restrict__ Woth, unsigned short* __restrict__ Wotl)
{
    const int b = blockIdx.x, tid = threadIdx.x;
    __shared__ float ld[64 * 68];
    float4* ld4 = reinterpret_cast<float4*>(ld);

    if (b < 192) {
        const int wi = b;                    // 0..191
        const int idx = wi >> 3;             // p*8+h
        const int kt = wi & 7;               // k-tile of 64
        const int p = idx >> 3, h = idx & 7;
        const float* src = ((p == 0) ? Wq : (p == 1) ? Wk : Wv)
                         + (size_t)h * 512 * 64 + (size_t)kt * 64 * 64;
        unsigned short* dst = Wt + (size_t)idx * 64 * 512 + kt * 64;
        const int rr = tid >> 4, c4 = tid & 15;
        #pragma unroll
        for (int it = 0; it < 4; it++) {
            int r = rr + 16 * it;            // k-row in tile
            ld4[r * 17 + c4] = reinterpret_cast<const float4*>(src + (size_t)r * 64)[c4];
        }
        __syncthreads();
        #pragma unroll
        for (int it = 0; it < 2; it++) {
            int slot = tid + it * 256;
            int n = slot >> 3, g = slot & 7;
            us8 o;
            #pragma unroll
            for (int i = 0; i < 8; i++)
                o[i] = f2bf(ld[(g * 8 + i) * 68 + n]);
            *reinterpret_cast<us8*>(dst + (size_t)n * 512 + g * 8) = o;
        }
    } else {
        const int ti = b - 192;              // 0..63
        const int kt = ti >> 3, nt = ti & 7;
        const float* src = Wo + (size_t)kt * 64 * 512 + nt * 64;
        const int rr = tid >> 4, c4 = tid & 15;
        #pragma unroll
        for (int it = 0; it < 4; it++) {
            int r = rr + 16 * it;
            ld4[r * 17 + c4] = reinterpret_cast<const float4*>(src + (size_t)r * 512)[c4];
        }
        __syncthreads();
        #pragma unroll
        for (int it = 0; it < 2; it++) {
            int slot = tid + it * 256;
            int n = slot >> 3, g = slot & 7;
            us8 oh, ol;
            #pragma unroll
            for (int i = 0; i < 8; i++) {
                float v = ld[(g * 8 + i) * 68 + n];
                unsigned short hi = f2bf(v);
                oh[i] = hi;
                ol[i] = f2bf(v - bf2f(hi));
            }
            size_t doff = (size_t)(nt * 64 + n) * 512 + kt * 64 + g * 8;
            *reinterpret_cast<us8*>(Woth + doff) = oh;
            *reinterpret_cast<us8*>(Wotl + doff) = ol;
        }
    }
}

// ---------------------------------------------------------------------------
// Kernel 1: QKV projections via bf16 MFMA, double-buffered LDS, ONE barrier
// per K-chunk. grid (32, 8, 3), block 256 (4 waves).  fp32 A-side converted
// inline during staging (R8-proven).  Q prescaled by 0.125*log2(e).
// ---------------------------------------------------------------------------
__global__ __launch_bounds__(256) void qkv_mfma(
    const float* __restrict__ emb, const float* __restrict__ Kin,
    const float* __restrict__ Vin, const unsigned short* __restrict__ Wt,
    const float* __restrict__ bq, const float* __restrict__ bk, const float* __restrict__ bv,
    unsigned short* __restrict__ qo, unsigned short* __restrict__ ko, unsigned short* __restrict__ vo)
{
    const int p = blockIdx.z, h = blockIdx.y, s0 = blockIdx.x * 64;
    const float* X = (p == 0) ? emb : (p == 1) ? Kin : Vin;
    const unsigned short* W = Wt + (size_t)(p * 8 + h) * 64 * 512;
    const float* B = ((p == 0) ? bq : (p == 1) ? bk : bv) + h * 64;

    const int tid = threadIdx.x;
    const int w = tid >> 6, lane = tid & 63, cl = lane & 15, q4 = lane >> 4;
    const int sr = tid >> 3, sg = tid & 7;

    __shared__ unsigned short As[2][64 * 72];
    __shared__ unsigned short Bs[2][64 * 72];

    // stage chunk 0
    #pragma unroll
    for (int it = 0; it < 2; it++) {
        int r = sr + 32 * it;
        const float4* xs = reinterpret_cast<const float4*>(&X[(size_t)(s0 + r) * 512 + sg * 8]);
        float4 f0 = xs[0], f1 = xs[1];
        us8 o;
        o[0] = f2bf(f0.x); o[1] = f2bf(f0.y); o[2] = f2bf(f0.z); o[3] = f2bf(f0.w);
        o[4] = f2bf(f1.x); o[5] = f2bf(f1.y); o[6] = f2bf(f1.z); o[7] = f2bf(f1.w);
        *reinterpret_cast<us8*>(&As[0][r * 72 + sg * 8]) = o;
        *reinterpret_cast<float4*>(&Bs[0][r * 72 + sg * 8]) =
            *reinterpret_cast<const float4*>(&W[(size_t)r * 512 + sg * 8]);
    }

    f32x4 acc[4] = {};

    for (int c = 0; c < 8; c++) {
        __syncthreads();
        const int buf = c & 1;
        const bool more = (c + 1 < 8);
        float4 ar[2][2], br[2];
        if (more) {
            #pragma unroll
            for (int it = 0; it < 2; it++) {
                int r = sr + 32 * it;
                const float4* xs = reinterpret_cast<const float4*>(
                    &X[(size_t)(s0 + r) * 512 + (c + 1) * 64 + sg * 8]);
                ar[it][0] = xs[0];
                ar[it][1] = xs[1];
                br[it] = *reinterpret_cast<const float4*>(
                    &W[(size_t)r * 512 + (c + 1) * 64 + sg * 8]);
            }
        }

        bf16x8 a0 = *reinterpret_cast<const bf16x8*>(&As[buf][(16 * w + cl) * 72 + q4 * 8]);
        bf16x8 a1 = *reinterpret_cast<const bf16x8*>(&As[buf][(16 * w + cl) * 72 + 32 + q4 * 8]);
        #pragma unroll
        for (int nn = 0; nn < 4; nn++) {
            bf16x8 b0 = *reinterpret_cast<const bf16x8*>(&Bs[buf][(16 * nn + cl) * 72 + q4 * 8]);
            bf16x8 b1 = *reinterpret_cast<const bf16x8*>(&Bs[buf][(16 * nn + cl) * 72 + 32 + q4 * 8]);
            acc[nn] = __builtin_amdgcn_mfma_f32_16x16x32_bf16(a0, b0, acc[nn], 0, 0, 0);
            acc[nn] = __builtin_amdgcn_mfma_f32_16x16x32_bf16(a1, b1, acc[nn], 0, 0, 0);
        }

        if (more) {
            const int nbuf = buf ^ 1;
            #pragma unroll
            for (int it = 0; it < 2; it++) {
                int r = sr + 32 * it;
                us8 o;
                o[0] = f2bf(ar[it][0].x); o[1] = f2bf(ar[it][0].y);
                o[2] = f2bf(ar[it][0].z); o[3] = f2bf(ar[it][0].w);
                o[4] = f2bf(ar[it][1].x); o[5] = f2bf(ar[it][1].y);
                o[6] = f2bf(ar[it][1].z); o[7] = f2bf(ar[it][1].w);
                *reinterpret_cast<us8*>(&As[nbuf][r * 72 + sg * 8]) = o;
                *reinterpret_cast<float4*>(&Bs[nbuf][r * 72 + sg * 8]) = br[it];
            }
        }
    }

    if (p == 0) {
        const float QSCALE = 0.125f * 1.4426950408889634f;
        #pragma unroll
        for (int nn = 0; nn < 4; nn++) {
            int col = 16 * nn + cl;
            float bb = B[col];
            #pragma unroll
            for (int r = 0; r < 4; r++)
                qo[((size_t)h * SQ + s0 + 16 * w + q4 * 4 + r) * 64 + col] =
                    f2bf((acc[nn][r] + bb) * QSCALE);
        }
    } else if (p == 1) {
        #pragma unroll
        for (int nn = 0; nn < 4; nn++) {
            int col = 16 * nn + cl;
            float bb = B[col];
            #pragma unroll
            for (int r = 0; r < 4; r++)
                ko[((size_t)h * SQ + s0 + 16 * w + q4 * 4 + r) * 64 + col] =
                    f2bf(acc[nn][r] + bb);
        }
    } else {
        #pragma unroll
        for (int nn = 0; nn < 4; nn++) {
            int col = 16 * nn + cl;   // dv
            float bb = B[col];
            ushort4 o;
            o.x = f2bf(acc[nn][0] + bb);
            o.y = f2bf(acc[nn][1] + bb);
            o.z = f2bf(acc[nn][2] + bb);
            o.w = f2bf(acc[nn][3] + bb);
            *reinterpret_cast<ushort4*>(
                vo + ((size_t)h * 64 + col) * SQ + s0 + 16 * w + q4 * 4) = o;
        }
    }
}

// ---------------------------------------------------------------------------
// Kernel 2: flash attention with 2D wave split (q-half x tile-parity).
//
// grid (32, 8, 4), block 256 = 4 waves, launch_bounds(256,4) -> 4 blocks/CU.
// Wave (qh = w>>1, tp = w&1) computes 32 q-rows over tiles of parity tp.
// Each K/V tile is read by TWO waves instead of four -> LDS read bytes
// halve vs R1 (the validated 12.8us was LDS-throughput-bound).  Both
// parities live in the Ks/Vs buffers simultaneously; compute -> barrier ->
// stage both next tiles -> barrier (1 barrier/tile, same as R1).  The
// parity-split O/l partials merge at the end through a 17KB LDS exchange
// that REUSES the K/V buffers (no extra LDS, occupancy preserved).
// VGPR ledger ~115 < 128.  Swapped QK^T + kapA V permutation as R1.
// ---------------------------------------------------------------------------
#define PW 72

__global__ __launch_bounds__(256, 4) void attn_fwd(
    const unsigned short* __restrict__ qbf,   // [h][2048][64], *0.125*log2e folded
    const unsigned short* __restrict__ kbf,   // [h][2048][64]
    const unsigned short* __restrict__ vbf,   // [h][64][2048] transposed
    float* __restrict__ Opart,                // [4][8][2048][64]
    float* __restrict__ lpart)                // [4][8][2048]
{
    const int h = blockIdx.y, s0 = blockIdx.x * 64, z = blockIdx.z;
    const int tid = threadIdx.x;
    const int w = tid >> 6, lane = tid & 63, cl = lane & 15, q4 = lane >> 4;
    const int qh = w >> 1, tp = w & 1;
    const int NT = SQ / 64 / NSPLIT;          // 8 tiles per block
    const int t0 = z * NT;

    __shared__ unsigned short SH[4 * 64 * PW];   // Ks[0],Ks[1],Vs[0],Vs[1]

    // Q fragments: this wave's 32 q-rows (two 16-row subtiles)
    bf16x8 aq[2][2];
    #pragma unroll
    for (int qs = 0; qs < 2; qs++) {
        const unsigned short* qb =
            &qbf[((size_t)h * SQ + s0 + 32 * qh + 16 * qs + cl) * 64 + q4 * 8];
        aq[qs][0] = *reinterpret_cast<const bf16x8*>(qb);
        aq[qs][1] = *reinterpret_cast<const bf16x8*>(qb + 32);
    }

    const int sr = tid >> 3, sg = tid & 7;
    const int kapA = 32 * (sg >> 2) + 16 * (sg & 1) + 4 * ((sg >> 1) & 1);

    // cooperative staging of tile t into parity buffer par
    auto stage = [&](int par, int t) {
        unsigned short* Kd = &SH[par * 64 * PW];
        unsigned short* Vd = &SH[(2 + par) * 64 * PW];
        #pragma unroll
        for (int it = 0; it < 2; it++) {
            int r = sr + 32 * it;
            *reinterpret_cast<float4*>(&Kd[r * PW + sg * 8]) =
                *reinterpret_cast<const float4*>(&kbf[((size_t)h * SQ + t * 64 + r) * 64 + sg * 8]);
            us8 vv = *reinterpret_cast<const us8*>(&vbf[((size_t)h * 64 + r) * SQ + t * 64 + sg * 8]);
            *reinterpret_cast<us4*>(&Vd[r * PW + kapA]) =
                __builtin_shufflevector(vv, vv, 0, 1, 2, 3);
            *reinterpret_cast<us4*>(&Vd[r * PW + kapA + 8]) =
                __builtin_shufflevector(vv, vv, 4, 5, 6, 7);
        }
    };

    stage(0, t0);
    stage(1, t0 + 1);
    __syncthreads();

    f32x4 o_acc[2][4] = {};
    float lsum[2] = {};
    const unsigned short* Kb = &SH[tp * 64 * PW];
    const unsigned short* Vb = &SH[(2 + tp) * 64 * PW];

    for (int pr = 0; pr < NT / 2; pr++) {
        // ---- compute my parity's tile (t0 + 2*pr + tp) ----
        f32x4 s_acc[2][4] = {};
        #pragma unroll
        for (int nn = 0; nn < 4; nn++) {
            bf16x8 k0 = *reinterpret_cast<const bf16x8*>(&Kb[(16 * nn + cl) * PW + q4 * 8]);
            bf16x8 k1 = *reinterpret_cast<const bf16x8*>(&Kb[(16 * nn + cl) * PW + 32 + q4 * 8]);
            #pragma unroll
            for (int qs = 0; qs < 2; qs++) {
                s_acc[qs][nn] = __builtin_amdgcn_mfma_f32_16x16x32_bf16(k0, aq[qs][0], s_acc[qs][nn], 0, 0, 0);
                s_acc[qs][nn] = __builtin_amdgcn_mfma_f32_16x16x32_bf16(k1, aq[qs][1], s_acc[qs][nn], 0, 0, 0);
            }
        }

        bf16x8 ap[2][2];
        #pragma unroll
        for (int qs = 0; qs < 2; qs++)
            #pragma unroll
            for (int nn = 0; nn < 4; nn++)
                #pragma unroll
                for (int r = 0; r < 4; r++) {
                    float pv = __builtin_amdgcn_exp2f(s_acc[qs][nn][r]);
                    lsum[qs] += pv;
                    ap[qs][nn >> 1][(nn & 1) * 4 + r] = (__bf16)pv;
                }

        #pragma unroll
        for (int nn = 0; nn < 4; nn++) {
            bf16x8 b0 = *reinterpret_cast<const bf16x8*>(&Vb[(16 * nn + cl) * PW + q4 * 8]);
            bf16x8 b1 = *reinterpret_cast<const bf16x8*>(&Vb[(16 * nn + cl) * PW + 32 + q4 * 8]);
            #pragma unroll
            for (int qs = 0; qs < 2; qs++) {
                o_acc[qs][nn] = __builtin_amdgcn_mfma_f32_16x16x32_bf16(ap[qs][0], b0, o_acc[qs][nn], 0, 0, 0);
                o_acc[qs][nn] = __builtin_amdgcn_mfma_f32_16x16x32_bf16(ap[qs][1], b1, o_acc[qs][nn], 0, 0, 0);
            }
        }

        __syncthreads();                      // all waves done reading both bufs
        if (pr + 1 < NT / 2) {
            stage(0, t0 + 2 * pr + 2);
            stage(1, t0 + 2 * pr + 3);
            __syncthreads();                  // staged data visible
        }
    }

    // ---- merge parity halves through LDS (reuses K/V space) ----
    __syncthreads();
    float* Ox = reinterpret_cast<float*>(SH);         // 2*2*4*256 floats = 16 KB
    float* Lx = Ox + 4096;                            // 256 floats
    if (tp == 1) {
        #pragma unroll
        for (int qs = 0; qs < 2; qs++) {
            #pragma unroll
            for (int nn = 0; nn < 4; nn++)
                *reinterpret_cast<f32x4*>(&Ox[(((qh * 2 + qs) * 4 + nn) * 256) + lane * 4]) =
                    o_acc[qs][nn];
            Lx[(qh * 2 + qs) * 64 + lane] = lsum[qs];
        }
    }
    __syncthreads();
    if (tp == 0) {
        const size_t zb = (size_t)(z * NH + h);
        #pragma unroll
        for (int qs = 0; qs < 2; qs++) {
            #pragma unroll
            for (int nn = 0; nn < 4; nn++)
                o_acc[qs][nn] += *reinterpret_cast<const f32x4*>(
                    &Ox[(((qh * 2 + qs) * 4 + nn) * 256) + lane * 4]);
            float v = lsum[qs] + Lx[(qh * 2 + qs) * 64 + lane];
            v += __shfl_xor(v, 16);
            v += __shfl_xor(v, 32);
            if (q4 == 0)
                lpart[zb * SQ + s0 + 32 * qh + 16 * qs + cl] = v;
            #pragma unroll
            for (int nn = 0; nn < 4; nn++)
                #pragma unroll
                for (int r = 0; r < 4; r++)
                    Opart[(zb * SQ + s0 + 32 * qh + 16 * qs + 4 * q4 + r) * 64 + 16 * nn + cl] =
                        o_acc[qs][nn][r];
        }
    }
}

// ---------------------------------------------------------------------------
// Kernel 2b: combine KV-split partials, normalize, hi/lo split. 512 blocks.
// ---------------------------------------------------------------------------
__global__ __launch_bounds__(256) void attn_combine(
    const float* __restrict__ Opart, const float* __restrict__ lpart,
    unsigned short* __restrict__ athi, unsigned short* __restrict__ atlo)
{
    const int gid = blockIdx.x * 256 + threadIdx.x;   // 131072
    const int s = gid >> 6, oct = gid & 63;
    const int col0 = oct * 8, h = col0 >> 6, dv0 = col0 & 63;

    float l = 0.f;
    #pragma unroll
    for (int z = 0; z < NSPLIT; z++)
        l += lpart[(size_t)(z * NH + h) * SQ + s];
    const float inv = 1.0f / l;

    float o[8] = {};
    #pragma unroll
    for (int z = 0; z < NSPLIT; z++) {
        const float4* base = reinterpret_cast<const float4*>(
            Opart + ((size_t)(z * NH + h) * SQ + s) * 64 + dv0);
        float4 a = base[0], bq = base[1];
        o[0] += a.x; o[1] += a.y; o[2] += a.z; o[3] += a.w;
        o[4] += bq.x; o[5] += bq.y; o[6] += bq.z; o[7] += bq.w;
    }
    us8 hi, lo;
    #pragma unroll
    for (int i = 0; i < 8; i++) {
        float v = o[i] * inv;
        unsigned short hb = f2bf(v);
        hi[i] = hb;
        lo[i] = f2bf(v - bf2f(hb));
    }
    *reinterpret_cast<us8*>(athi + (size_t)s * DM + col0) = hi;
    *reinterpret_cast<us8*>(atlo + (size_t)s * DM + col0) = lo;
}

// ---------------------------------------------------------------------------
// Kernel 3: output projection (R1-proven version), compensated split-bf16
// MFMA, double-buffered LDS with ONE barrier per K-chunk. grid (32, 8).
// ---------------------------------------------------------------------------
__global__ __launch_bounds__(256) void out_proj(
    const unsigned short* __restrict__ ah, const unsigned short* __restrict__ al,
    const unsigned short* __restrict__ Wh, const unsigned short* __restrict__ Wl,
    const float* __restrict__ bo, float* __restrict__ out)
{
    const int s0 = blockIdx.x * 64, n0 = blockIdx.y * 64;
    const int tid = threadIdx.x;
    const int w = tid >> 6, lane = tid & 63, cl = lane & 15, q4 = lane >> 4;
    const int sr = tid >> 3, sg = tid & 7;

    __shared__ unsigned short Ah[2][64 * 72], Al[2][64 * 72];
    __shared__ unsigned short Bh[2][64 * 72], Bl[2][64 * 72];

    #pragma unroll
    for (int it = 0; it < 2; it++) {
        int r = sr + 32 * it;
        *reinterpret_cast<float4*>(&Ah[0][r * 72 + sg * 8]) =
            *reinterpret_cast<const float4*>(&ah[(size_t)(s0 + r) * 512 + sg * 8]);
        *reinterpret_cast<float4*>(&Al[0][r * 72 + sg * 8]) =
            *reinterpret_cast<const float4*>(&al[(size_t)(s0 + r) * 512 + sg * 8]);
        *reinterpret_cast<float4*>(&Bh[0][r * 72 + sg * 8]) =
            *reinterpret_cast<const float4*>(&Wh[(size_t)(n0 + r) * 512 + sg * 8]);
        *reinterpret_cast<float4*>(&Bl[0][r * 72 + sg * 8]) =
            *reinterpret_cast<const float4*>(&Wl[(size_t)(n0 + r) * 512 + sg * 8]);
    }

    f32x4 acc[4] = {};

    for (int c = 0; c < 8; c++) {
        __syncthreads();
        const int buf = c & 1;
        const bool more = (c + 1 < 8);
        float4 ahr[2], alr[2], bhr[2], blr[2];
        if (more) {
            #pragma unroll
            for (int it = 0; it < 2; it++) {
                int r = sr + 32 * it;
                int off = (c + 1) * 64 + sg * 8;
                ahr[it] = *reinterpret_cast<const float4*>(&ah[(size_t)(s0 + r) * 512 + off]);
                alr[it] = *reinterpret_cast<const float4*>(&al[(size_t)(s0 + r) * 512 + off]);
                bhr[it] = *reinterpret_cast<const float4*>(&Wh[(size_t)(n0 + r) * 512 + off]);
                blr[it] = *reinterpret_cast<const float4*>(&Wl[(size_t)(n0 + r) * 512 + off]);
            }
        }

        bf16x8 ah0 = *reinterpret_cast<const bf16x8*>(&Ah[buf][(16 * w + cl) * 72 + q4 * 8]);
        bf16x8 ah1 = *reinterpret_cast<const bf16x8*>(&Ah[buf][(16 * w + cl) * 72 + 32 + q4 * 8]);
        bf16x8 al0 = *reinterpret_cast<const bf16x8*>(&Al[buf][(16 * w + cl) * 72 + q4 * 8]);
        bf16x8 al1 = *reinterpret_cast<const bf16x8*>(&Al[buf][(16 * w + cl) * 72 + 32 + q4 * 8]);
        #pragma unroll
        for (int nn = 0; nn < 4; nn++) {
            bf16x8 bh0 = *reinterpret_cast<const bf16x8*>(&Bh[buf][(16 * nn + cl) * 72 + q4 * 8]);
            bf16x8 bh1 = *reinterpret_cast<const bf16x8*>(&Bh[buf][(16 * nn + cl) * 72 + 32 + q4 * 8]);
            bf16x8 bl0 = *reinterpret_cast<const bf16x8*>(&Bl[buf][(16 * nn + cl) * 72 + q4 * 8]);
            bf16x8 bl1 = *reinterpret_cast<const bf16x8*>(&Bl[buf][(16 * nn + cl) * 72 + 32 + q4 * 8]);
            acc[nn] = __builtin_amdgcn_mfma_f32_16x16x32_bf16(ah0, bh0, acc[nn], 0, 0, 0);
            acc[nn] = __builtin_amdgcn_mfma_f32_16x16x32_bf16(ah1, bh1, acc[nn], 0, 0, 0);
            acc[nn] = __builtin_amdgcn_mfma_f32_16x16x32_bf16(ah0, bl0, acc[nn], 0, 0, 0);
            acc[nn] = __builtin_amdgcn_mfma_f32_16x16x32_bf16(ah1, bl1, acc[nn], 0, 0, 0);
            acc[nn] = __builtin_amdgcn_mfma_f32_16x16x32_bf16(al0, bh0, acc[nn], 0, 0, 0);
            acc[nn] = __builtin_amdgcn_mfma_f32_16x16x32_bf16(al1, bh1, acc[nn], 0, 0, 0);
        }

        if (more) {
            const int nbuf = buf ^ 1;
            #pragma unroll
            for (int it = 0; it < 2; it++) {
                int r = sr + 32 * it;
                *reinterpret_cast<float4*>(&Ah[nbuf][r * 72 + sg * 8]) = ahr[it];
                *reinterpret_cast<float4*>(&Al[nbuf][r * 72 + sg * 8]) = alr[it];
                *reinterpret_cast<float4*>(&Bh[nbuf][r * 72 + sg * 8]) = bhr[it];
                *reinterpret_cast<float4*>(&Bl[nbuf][r * 72 + sg * 8]) = blr[it];
            }
        }
    }

    #pragma unroll
    for (int nn = 0; nn < 4; nn++) {
        int col = n0 + 16 * nn + cl;
        float bb = bo[col];
        #pragma unroll
        for (int r = 0; r < 4; r++)
            out[(size_t)(s0 + 16 * w + q4 * 4 + r) * DM + col] = acc[nn][r] + bb;
    }
}

extern "C" void kernel_launch(void* const* d_in, const int* in_sizes, int n_in,
                              void* d_out, int out_size, void* d_ws, size_t ws_size,
                              hipStream_t stream) {
    const float* emb = (const float*)d_in[0];
    const float* Kin = (const float*)d_in[1];
    const float* Vin = (const float*)d_in[2];
    const float* Wq  = (const float*)d_in[3];
    const float* bq  = (const float*)d_in[4];
    const float* Wk  = (const float*)d_in[5];
    const float* bk  = (const float*)d_in[6];
    const float* Wv  = (const float*)d_in[7];
    const float* bv  = (const float*)d_in[8];
    const float* Wo  = (const float*)d_in[9];
    const float* bo  = (const float*)d_in[10];
    float* out = (float*)d_out;

    unsigned short* p = (unsigned short*)d_ws;
    unsigned short* Wt   = p; p += (size_t)24 * 64 * 512;
    unsigned short* Woth = p; p += (size_t)512 * 512;
    unsigned short* Wotl = p; p += (size_t)512 * 512;
    unsigned short* qbf  = p; p += (size_t)NH * SQ * 64;
    unsigned short* kbf  = p; p += (size_t)NH * SQ * 64;
    unsigned short* vbf  = p; p += (size_t)NH * SQ * 64;
    unsigned short* athi = p; p += (size_t)SQ * DM;
    unsigned short* atlo = p; p += (size_t)SQ * DM;
    float* Opart = (float*)p;                                   // 16 MB
    float* lpart = Opart + (size_t)NSPLIT * NH * SQ * 64;       // 256 KB

    convert_w<<<256, 256, 0, stream>>>(Wq, Wk, Wv, Wo, Wt, Woth, Wotl);
    qkv_mfma<<<dim3(32, 8, 3), 256, 0, stream>>>(emb, Kin, Vin, Wt, bq, bk, bv,
                                                 qbf, kbf, vbf);
    attn_fwd<<<dim3(32, 8, NSPLIT), 256, 0, stream>>>(qbf, kbf, vbf, Opart, lpart);
    attn_combine<<<512, 256, 0, stream>>>(Opart, lpart, athi, atlo);
    out_proj<<<dim3(32, 8), 256, 0, stream>>>(athi, atlo, Woth, Wotl, bo, out);
}

// Round 10
// 119.425 us; speedup vs baseline: 1.0582x; 1.0582x over previous
//
#include <hip/hip_runtime.h>

#define SQ 2048
#define DM 512
#define NH 8
#define NSPLIT 4

typedef __bf16 bf16x8 __attribute__((ext_vector_type(8)));
typedef float f32x4 __attribute__((ext_vector_type(4)));
typedef unsigned short us8 __attribute__((ext_vector_type(8)));
typedef unsigned short us4 __attribute__((ext_vector_type(4)));

__device__ __forceinline__ unsigned short f2bf(float f) {
    unsigned u = __builtin_bit_cast(unsigned, f);
    u += 0x7fffu + ((u >> 16) & 1u);     // round-to-nearest-even
    return (unsigned short)(u >> 16);
}
__device__ __forceinline__ float bf2f(unsigned short u) {
    return __builtin_bit_cast(float, (unsigned)u << 16);
}

// ---------------------------------------------------------------------------
// Kernel 0: WEIGHT conversions only (emb/K/V conversion fused into qkv_mfma).
// ---------------------------------------------------------------------------
__global__ __launch_bounds__(256) void convert_w(
    const float* __restrict__ Wq,  const float* __restrict__ Wk,  const float* __restrict__ Wv,
    const float* __restrict__ Wo,
    unsigned short* __restrict__ Wt,
    unsigned short* __restrict__ Woth, unsigned short* __restrict__ Wotl)
{
    const int b = blockIdx.x, tid = threadIdx.x;
    __shared__ float ld[64 * 68];
    float4* ld4 = reinterpret_cast<float4*>(ld);

    if (b < 192) {
        const int wi = b;                    // 0..191
        const int idx = wi >> 3;             // p*8+h
        const int kt = wi & 7;               // k-tile of 64
        const int p = idx >> 3, h = idx & 7;
        const float* src = ((p == 0) ? Wq : (p == 1) ? Wk : Wv)
                         + (size_t)h * 512 * 64 + (size_t)kt * 64 * 64;
        unsigned short* dst = Wt + (size_t)idx * 64 * 512 + kt * 64;
        const int rr = tid >> 4, c4 = tid & 15;
        #pragma unroll
        for (int it = 0; it < 4; it++) {
            int r = rr + 16 * it;            // k-row in tile
            ld4[r * 17 + c4] = reinterpret_cast<const float4*>(src + (size_t)r * 64)[c4];
        }
        __syncthreads();
        #pragma unroll
        for (int it = 0; it < 2; it++) {
            int slot = tid + it * 256;
            int n = slot >> 3, g = slot & 7;
            us8 o;
            #pragma unroll
            for (int i = 0; i < 8; i++)
                o[i] = f2bf(ld[(g * 8 + i) * 68 + n]);
            *reinterpret_cast<us8*>(dst + (size_t)n * 512 + g * 8) = o;
        }
    } else {
        const int ti = b - 192;              // 0..63
        const int kt = ti >> 3, nt = ti & 7;
        const float* src = Wo + (size_t)kt * 64 * 512 + nt * 64;
        const int rr = tid >> 4, c4 = tid & 15;
        #pragma unroll
        for (int it = 0; it < 4; it++) {
            int r = rr + 16 * it;
            ld4[r * 17 + c4] = reinterpret_cast<const float4*>(src + (size_t)r * 512)[c4];
        }
        __syncthreads();
        #pragma unroll
        for (int it = 0; it < 2; it++) {
            int slot = tid + it * 256;
            int n = slot >> 3, g = slot & 7;
            us8 oh, ol;
            #pragma unroll
            for (int i = 0; i < 8; i++) {
                float v = ld[(g * 8 + i) * 68 + n];
                unsigned short hi = f2bf(v);
                oh[i] = hi;
                ol[i] = f2bf(v - bf2f(hi));
            }
            size_t doff = (size_t)(nt * 64 + n) * 512 + kt * 64 + g * 8;
            *reinterpret_cast<us8*>(Woth + doff) = oh;
            *reinterpret_cast<us8*>(Wotl + doff) = ol;
        }
    }
}

// ---------------------------------------------------------------------------
// Kernel 1: QKV projections via bf16 MFMA, double-buffered LDS, ONE barrier
// per K-chunk. grid (32, 8, 3), block 256 (4 waves).  fp32 A-side converted
// inline during staging (R8-proven).  Q prescaled by 0.125*log2(e).
// NEW: V^T (p==2) written via LDS transpose reusing As[0] -- the old path
// was 8B stores at 4KB stride (4-8x write amplification on 2MB).
// ---------------------------------------------------------------------------
__global__ __launch_bounds__(256) void qkv_mfma(
    const float* __restrict__ emb, const float* __restrict__ Kin,
    const float* __restrict__ Vin, const unsigned short* __restrict__ Wt,
    const float* __restrict__ bq, const float* __restrict__ bk, const float* __restrict__ bv,
    unsigned short* __restrict__ qo, unsigned short* __restrict__ ko, unsigned short* __restrict__ vo)
{
    const int p = blockIdx.z, h = blockIdx.y, s0 = blockIdx.x * 64;
    const float* X = (p == 0) ? emb : (p == 1) ? Kin : Vin;
    const unsigned short* W = Wt + (size_t)(p * 8 + h) * 64 * 512;
    const float* B = ((p == 0) ? bq : (p == 1) ? bk : bv) + h * 64;

    const int tid = threadIdx.x;
    const int w = tid >> 6, lane = tid & 63, cl = lane & 15, q4 = lane >> 4;
    const int sr = tid >> 3, sg = tid & 7;

    __shared__ unsigned short As[2][64 * 72];
    __shared__ unsigned short Bs[2][64 * 72];

    // stage chunk 0
    #pragma unroll
    for (int it = 0; it < 2; it++) {
        int r = sr + 32 * it;
        const float4* xs = reinterpret_cast<const float4*>(&X[(size_t)(s0 + r) * 512 + sg * 8]);
        float4 f0 = xs[0], f1 = xs[1];
        us8 o;
        o[0] = f2bf(f0.x); o[1] = f2bf(f0.y); o[2] = f2bf(f0.z); o[3] = f2bf(f0.w);
        o[4] = f2bf(f1.x); o[5] = f2bf(f1.y); o[6] = f2bf(f1.z); o[7] = f2bf(f1.w);
        *reinterpret_cast<us8*>(&As[0][r * 72 + sg * 8]) = o;
        *reinterpret_cast<float4*>(&Bs[0][r * 72 + sg * 8]) =
            *reinterpret_cast<const float4*>(&W[(size_t)r * 512 + sg * 8]);
    }

    f32x4 acc[4] = {};

    for (int c = 0; c < 8; c++) {
        __syncthreads();
        const int buf = c & 1;
        const bool more = (c + 1 < 8);
        float4 ar[2][2], br[2];
        if (more) {
            #pragma unroll
            for (int it = 0; it < 2; it++) {
                int r = sr + 32 * it;
                const float4* xs = reinterpret_cast<const float4*>(
                    &X[(size_t)(s0 + r) * 512 + (c + 1) * 64 + sg * 8]);
                ar[it][0] = xs[0];
                ar[it][1] = xs[1];
                br[it] = *reinterpret_cast<const float4*>(
                    &W[(size_t)r * 512 + (c + 1) * 64 + sg * 8]);
            }
        }

        bf16x8 a0 = *reinterpret_cast<const bf16x8*>(&As[buf][(16 * w + cl) * 72 + q4 * 8]);
        bf16x8 a1 = *reinterpret_cast<const bf16x8*>(&As[buf][(16 * w + cl) * 72 + 32 + q4 * 8]);
        #pragma unroll
        for (int nn = 0; nn < 4; nn++) {
            bf16x8 b0 = *reinterpret_cast<const bf16x8*>(&Bs[buf][(16 * nn + cl) * 72 + q4 * 8]);
            bf16x8 b1 = *reinterpret_cast<const bf16x8*>(&Bs[buf][(16 * nn + cl) * 72 + 32 + q4 * 8]);
            acc[nn] = __builtin_amdgcn_mfma_f32_16x16x32_bf16(a0, b0, acc[nn], 0, 0, 0);
            acc[nn] = __builtin_amdgcn_mfma_f32_16x16x32_bf16(a1, b1, acc[nn], 0, 0, 0);
        }

        if (more) {
            const int nbuf = buf ^ 1;
            #pragma unroll
            for (int it = 0; it < 2; it++) {
                int r = sr + 32 * it;
                us8 o;
                o[0] = f2bf(ar[it][0].x); o[1] = f2bf(ar[it][0].y);
                o[2] = f2bf(ar[it][0].z); o[3] = f2bf(ar[it][0].w);
                o[4] = f2bf(ar[it][1].x); o[5] = f2bf(ar[it][1].y);
                o[6] = f2bf(ar[it][1].z); o[7] = f2bf(ar[it][1].w);
                *reinterpret_cast<us8*>(&As[nbuf][r * 72 + sg * 8]) = o;
                *reinterpret_cast<float4*>(&Bs[nbuf][r * 72 + sg * 8]) = br[it];
            }
        }
    }

    if (p == 0) {
        const float QSCALE = 0.125f * 1.4426950408889634f;
        #pragma unroll
        for (int nn = 0; nn < 4; nn++) {
            int col = 16 * nn + cl;
            float bb = B[col];
            #pragma unroll
            for (int r = 0; r < 4; r++)
                qo[((size_t)h * SQ + s0 + 16 * w + q4 * 4 + r) * 64 + col] =
                    f2bf((acc[nn][r] + bb) * QSCALE);
        }
    } else if (p == 1) {
        #pragma unroll
        for (int nn = 0; nn < 4; nn++) {
            int col = 16 * nn + cl;
            float bb = B[col];
            #pragma unroll
            for (int r = 0; r < 4; r++)
                ko[((size_t)h * SQ + s0 + 16 * w + q4 * 4 + r) * 64 + col] =
                    f2bf(acc[nn][r] + bb);
        }
    } else {
        // V^T via LDS transpose: As[0] is free (last chunk reads buf 1 only,
        // and all waves synced past buf-0 reads at chunk 7's barrier).
        unsigned short* scr = &As[0][0];     // [col 0..63][row 0..63], stride 72
        #pragma unroll
        for (int nn = 0; nn < 4; nn++) {
            int col = 16 * nn + cl;
            float bb = B[col];
            us4 o;
            o[0] = f2bf(acc[nn][0] + bb);
            o[1] = f2bf(acc[nn][1] + bb);
            o[2] = f2bf(acc[nn][2] + bb);
            o[3] = f2bf(acc[nn][3] + bb);
            *reinterpret_cast<us4*>(&scr[col * 72 + 16 * w + 4 * q4]) = o;
        }
        __syncthreads();
        #pragma unroll
        for (int it = 0; it < 2; it++) {
            int slot = tid + it * 256;
            int n = slot >> 3, g = slot & 7;  // n = dv row of vo, g = s-octet
            *reinterpret_cast<us8*>(&vo[((size_t)h * 64 + n) * SQ + s0 + g * 8]) =
                *reinterpret_cast<const us8*>(&scr[n * 72 + g * 8]);
        }
    }
}

// ---------------------------------------------------------------------------
// Kernel 2: flash attention (R1/R8-proven version, FROZEN). bf16 MFMA, no
// online max, KV-SPLIT x4: grid (32, 8, 4).  Swapped QK^T keeps P lane-local;
// k-permutation baked into V LDS staging (kapA).  P never touches LDS.
// 36.9 KB LDS -> 4 blocks/CU.
// ---------------------------------------------------------------------------
#define PW 72

__global__ __launch_bounds__(256, 4) void attn_fwd(
    const unsigned short* __restrict__ qbf,   // [h][2048][64], *0.125*log2e folded
    const unsigned short* __restrict__ kbf,   // [h][2048][64]
    const unsigned short* __restrict__ vbf,   // [h][64][2048] transposed
    float* __restrict__ Opart,                // [4][8][2048][64]
    float* __restrict__ lpart)                // [4][8][2048]
{
    const int h = blockIdx.y, s0 = blockIdx.x * 64, z = blockIdx.z;
    const int tid = threadIdx.x;
    const int w = tid >> 6, lane = tid & 63, cl = lane & 15, q4 = lane >> 4;
    const int NT = SQ / 64 / NSPLIT;          // 8 tiles per block
    const int t0 = z * NT;

    __shared__ unsigned short Ks[2][64 * PW];
    __shared__ unsigned short Vs[2][64 * PW];

    // Q rows for this wave (B-operand fragment; same layout as A: row=cl)
    bf16x8 aq0 = *reinterpret_cast<const bf16x8*>(
        &qbf[((size_t)h * SQ + s0 + 16 * w + cl) * 64 + q4 * 8]);
    bf16x8 aq1 = *reinterpret_cast<const bf16x8*>(
        &qbf[((size_t)h * SQ + s0 + 16 * w + cl) * 64 + 32 + q4 * 8]);

    const int sr = tid >> 3, sg = tid & 7;
    // kappa position of this thread's V octet (t = 8*sg .. 8*sg+7):
    // first 4 values land at kapA, last 4 at kapA+8
    const int kapA = 32 * (sg >> 2) + 16 * (sg & 1) + 4 * ((sg >> 1) & 1);

    // stage first tile
    #pragma unroll
    for (int it = 0; it < 2; it++) {
        int r = sr + 32 * it;
        *reinterpret_cast<float4*>(&Ks[0][r * PW + sg * 8]) =
            *reinterpret_cast<const float4*>(&kbf[((size_t)h * SQ + t0 * 64 + r) * 64 + sg * 8]);
        us8 vv = *reinterpret_cast<const us8*>(&vbf[((size_t)h * 64 + r) * SQ + t0 * 64 + sg * 8]);
        *reinterpret_cast<us4*>(&Vs[0][r * PW + kapA]) =
            __builtin_shufflevector(vv, vv, 0, 1, 2, 3);
        *reinterpret_cast<us4*>(&Vs[0][r * PW + kapA + 8]) =
            __builtin_shufflevector(vv, vv, 4, 5, 6, 7);
    }

    f32x4 o_acc[4] = {};
    float lsum = 0.f;

    for (int tl = 0; tl < NT; tl++) {
        __syncthreads();
        const int buf = tl & 1;
        const bool more = (tl + 1 < NT);
        float4 kr[2];
        us8 vr[2];
        if (more) {
            #pragma unroll
            for (int it = 0; it < 2; it++) {
                int r = sr + 32 * it;
                kr[it] = *reinterpret_cast<const float4*>(
                    &kbf[((size_t)h * SQ + (t0 + tl + 1) * 64 + r) * 64 + sg * 8]);
                vr[it] = *reinterpret_cast<const us8*>(
                    &vbf[((size_t)h * 64 + r) * SQ + (t0 + tl + 1) * 64 + sg * 8]);
            }
        }

        // ---- S^T = K Q^T : lane(cl,q4) gets S[s=cl][t=16nn+4q4+r] ----
        f32x4 s_acc[4] = {};
        #pragma unroll
        for (int nn = 0; nn < 4; nn++) {
            bf16x8 k0 = *reinterpret_cast<const bf16x8*>(&Ks[buf][(16 * nn + cl) * PW + q4 * 8]);
            bf16x8 k1 = *reinterpret_cast<const bf16x8*>(&Ks[buf][(16 * nn + cl) * PW + 32 + q4 * 8]);
            s_acc[nn] = __builtin_amdgcn_mfma_f32_16x16x32_bf16(k0, aq0, s_acc[nn], 0, 0, 0);
            s_acc[nn] = __builtin_amdgcn_mfma_f32_16x16x32_bf16(k1, aq1, s_acc[nn], 0, 0, 0);
        }

        // ---- p = exp2(s) (log2e prescaled), in-register pack to A-frags ----
        bf16x8 ap0, ap1;
        #pragma unroll
        for (int nn = 0; nn < 4; nn++) {
            #pragma unroll
            for (int r = 0; r < 4; r++) {
                float pv = __builtin_amdgcn_exp2f(s_acc[nn][r]);
                lsum += pv;
                if (nn < 2) ap0[nn * 4 + r] = (__bf16)pv;
                else        ap1[(nn - 2) * 4 + r] = (__bf16)pv;
            }
        }

        // ---- O += P V  (A=P rows s, B=V^T rows dv, shared permuted k) ----
        #pragma unroll
        for (int nn = 0; nn < 4; nn++) {
            bf16x8 b0 = *reinterpret_cast<const bf16x8*>(&Vs[buf][(16 * nn + cl) * PW + q4 * 8]);
            bf16x8 b1 = *reinterpret_cast<const bf16x8*>(&Vs[buf][(16 * nn + cl) * PW + 32 + q4 * 8]);
            o_acc[nn] = __builtin_amdgcn_mfma_f32_16x16x32_bf16(ap0, b0, o_acc[nn], 0, 0, 0);
            o_acc[nn] = __builtin_amdgcn_mfma_f32_16x16x32_bf16(ap1, b1, o_acc[nn], 0, 0, 0);
        }

        if (more) {
            const int nbuf = buf ^ 1;
            #pragma unroll
            for (int it = 0; it < 2; it++) {
                int r = sr + 32 * it;
                *reinterpret_cast<float4*>(&Ks[nbuf][r * PW + sg * 8]) = kr[it];
                *reinterpret_cast<us4*>(&Vs[nbuf][r * PW + kapA]) =
                    __builtin_shufflevector(vr[it], vr[it], 0, 1, 2, 3);
                *reinterpret_cast<us4*>(&Vs[nbuf][r * PW + kapA + 8]) =
                    __builtin_shufflevector(vr[it], vr[it], 4, 5, 6, 7);
            }
        }
    }

    // each lane holds sum over its t-subset for s=cl; reduce across q4 groups
    lsum += __shfl_xor(lsum, 16);
    lsum += __shfl_xor(lsum, 32);

    const size_t zb = (size_t)(z * NH + h);
    if (q4 == 0)
        lpart[zb * SQ + s0 + 16 * w + cl] = lsum;

    #pragma unroll
    for (int nn = 0; nn < 4; nn++)
        #pragma unroll
        for (int r = 0; r < 4; r++)
            Opart[(zb * SQ + s0 + 16 * w + q4 * 4 + r) * 64 + 16 * nn + cl] = o_acc[nn][r];
}

// ---------------------------------------------------------------------------
// Kernel 2b: combine KV-split partials, normalize, hi/lo split. 512 blocks.
// ---------------------------------------------------------------------------
__global__ __launch_bounds__(256) void attn_combine(
    const float* __restrict__ Opart, const float* __restrict__ lpart,
    unsigned short* __restrict__ athi, unsigned short* __restrict__ atlo)
{
    const int gid = blockIdx.x * 256 + threadIdx.x;   // 131072
    const int s = gid >> 6, oct = gid & 63;
    const int col0 = oct * 8, h = col0 >> 6, dv0 = col0 & 63;

    float l = 0.f;
    #pragma unroll
    for (int z = 0; z < NSPLIT; z++)
        l += lpart[(size_t)(z * NH + h) * SQ + s];
    const float inv = 1.0f / l;

    float o[8] = {};
    #pragma unroll
    for (int z = 0; z < NSPLIT; z++) {
        const float4* base = reinterpret_cast<const float4*>(
            Opart + ((size_t)(z * NH + h) * SQ + s) * 64 + dv0);
        float4 a = base[0], bq = base[1];
        o[0] += a.x; o[1] += a.y; o[2] += a.z; o[3] += a.w;
        o[4] += bq.x; o[5] += bq.y; o[6] += bq.z; o[7] += bq.w;
    }
    us8 hi, lo;
    #pragma unroll
    for (int i = 0; i < 8; i++) {
        float v = o[i] * inv;
        unsigned short hb = f2bf(v);
        hi[i] = hb;
        lo[i] = f2bf(v - bf2f(hb));
    }
    *reinterpret_cast<us8*>(athi + (size_t)s * DM + col0) = hi;
    *reinterpret_cast<us8*>(atlo + (size_t)s * DM + col0) = lo;
}

// ---------------------------------------------------------------------------
// Kernel 3: output projection, compensated split-bf16 MFMA, double-buffered
// LDS, ONE barrier per K-chunk.  RESTRUCTURED for occupancy: 32-row s-tiles,
// grid (64, 8) = 512 blocks; LDS 54 KB -> 2 blocks/CU = 8 waves/CU (was
// 73.7 KB, 1 block/CU, 4 waves).  Waves = 2 row-strips x 2 nn-halves:
// reads/chunk-wave 20 -> 12.  A-side HBM traffic unchanged (half bytes per
// block x 2 blocks); B re-read 2x but Woth/Wotl = 1 MB, L2-resident.
// All fragments still come from LDS (R5 lesson: no fragment-layout global
// reads).  VGPR ~90.
// ---------------------------------------------------------------------------
__global__ __launch_bounds__(256, 2) void out_proj(
    const unsigned short* __restrict__ ah, const unsigned short* __restrict__ al,
    const unsigned short* __restrict__ Wh, const unsigned short* __restrict__ Wl,
    const float* __restrict__ bo, float* __restrict__ out)
{
    const int s0 = blockIdx.x * 32, n0 = blockIdx.y * 64;
    const int tid = threadIdx.x;
    const int w = tid >> 6, lane = tid & 63, cl = lane & 15, q4 = lane >> 4;
    const int rs = w & 1, nh = w >> 1;       // row strip / nn half per wave
    const int sr = tid >> 3, sg = tid & 7;   // sr 0..31

    __shared__ unsigned short Ah[2][32 * 72], Al[2][32 * 72];
    __shared__ unsigned short Bh[2][64 * 72], Bl[2][64 * 72];

    // stage chunk 0
    *reinterpret_cast<float4*>(&Ah[0][sr * 72 + sg * 8]) =
        *reinterpret_cast<const float4*>(&ah[(size_t)(s0 + sr) * 512 + sg * 8]);
    *reinterpret_cast<float4*>(&Al[0][sr * 72 + sg * 8]) =
        *reinterpret_cast<const float4*>(&al[(size_t)(s0 + sr) * 512 + sg * 8]);
    #pragma unroll
    for (int it = 0; it < 2; it++) {
        int r = sr + 32 * it;
        *reinterpret_cast<float4*>(&Bh[0][r * 72 + sg * 8]) =
            *reinterpret_cast<const float4*>(&Wh[(size_t)(n0 + r) * 512 + sg * 8]);
        *reinterpret_cast<float4*>(&Bl[0][r * 72 + sg * 8]) =
            *reinterpret_cast<const float4*>(&Wl[(size_t)(n0 + r) * 512 + sg * 8]);
    }

    f32x4 acc[2] = {};

    for (int c = 0; c < 8; c++) {
        __syncthreads();
        const int buf = c & 1;
        const bool more = (c + 1 < 8);
        float4 ahr, alr, bhr[2], blr[2];
        if (more) {
            int off = (c + 1) * 64 + sg * 8;
            ahr = *reinterpret_cast<const float4*>(&ah[(size_t)(s0 + sr) * 512 + off]);
            alr = *reinterpret_cast<const float4*>(&al[(size_t)(s0 + sr) * 512 + off]);
            #pragma unroll
            for (int it = 0; it < 2; it++) {
                int r = sr + 32 * it;
                bhr[it] = *reinterpret_cast<const float4*>(&Wh[(size_t)(n0 + r) * 512 + off]);
                blr[it] = *reinterpret_cast<const float4*>(&Wl[(size_t)(n0 + r) * 512 + off]);
            }
        }

        bf16x8 ah0 = *reinterpret_cast<const bf16x8*>(&Ah[buf][(16 * rs + cl) * 72 + q4 * 8]);
        bf16x8 ah1 = *reinterpret_cast<const bf16x8*>(&Ah[buf][(16 * rs + cl) * 72 + 32 + q4 * 8]);
        bf16x8 al0 = *reinterpret_cast<const bf16x8*>(&Al[buf][(16 * rs + cl) * 72 + q4 * 8]);
        bf16x8 al1 = *reinterpret_cast<const bf16x8*>(&Al[buf][(16 * rs + cl) * 72 + 32 + q4 * 8]);
        #pragma unroll
        for (int j = 0; j < 2; j++) {
            int nn = 2 * nh + j;
            bf16x8 bh0 = *reinterpret_cast<const bf16x8*>(&Bh[buf][(16 * nn + cl) * 72 + q4 * 8]);
            bf16x8 bh1 = *reinterpret_cast<const bf16x8*>(&Bh[buf][(16 * nn + cl) * 72 + 32 + q4 * 8]);
            bf16x8 bl0 = *reinterpret_cast<const bf16x8*>(&Bl[buf][(16 * nn + cl) * 72 + q4 * 8]);
            bf16x8 bl1 = *reinterpret_cast<const bf16x8*>(&Bl[buf][(16 * nn + cl) * 72 + 32 + q4 * 8]);
            acc[j] = __builtin_amdgcn_mfma_f32_16x16x32_bf16(ah0, bh0, acc[j], 0, 0, 0);
            acc[j] = __builtin_amdgcn_mfma_f32_16x16x32_bf16(ah1, bh1, acc[j], 0, 0, 0);
            acc[j] = __builtin_amdgcn_mfma_f32_16x16x32_bf16(ah0, bl0, acc[j], 0, 0, 0);
            acc[j] = __builtin_amdgcn_mfma_f32_16x16x32_bf16(ah1, bl1, acc[j], 0, 0, 0);
            acc[j] = __builtin_amdgcn_mfma_f32_16x16x32_bf16(al0, bh0, acc[j], 0, 0, 0);
            acc[j] = __builtin_amdgcn_mfma_f32_16x16x32_bf16(al1, bh1, acc[j], 0, 0, 0);
        }

        if (more) {
            const int nbuf = buf ^ 1;
            *reinterpret_cast<float4*>(&Ah[nbuf][sr * 72 + sg * 8]) = ahr;
            *reinterpret_cast<float4*>(&Al[nbuf][sr * 72 + sg * 8]) = alr;
            #pragma unroll
            for (int it = 0; it < 2; it++) {
                int r = sr + 32 * it;
                *reinterpret_cast<float4*>(&Bh[nbuf][r * 72 + sg * 8]) = bhr[it];
                *reinterpret_cast<float4*>(&Bl[nbuf][r * 72 + sg * 8]) = blr[it];
            }
        }
    }

    #pragma unroll
    for (int j = 0; j < 2; j++) {
        int nn = 2 * nh + j;
        int col = n0 + 16 * nn + cl;
        float bb = bo[col];
        #pragma unroll
        for (int r = 0; r < 4; r++)
            out[(size_t)(s0 + 16 * rs + q4 * 4 + r) * DM + col] = acc[j][r] + bb;
    }
}

extern "C" void kernel_launch(void* const* d_in, const int* in_sizes, int n_in,
                              void* d_out, int out_size, void* d_ws, size_t ws_size,
                              hipStream_t stream) {
    const float* emb = (const float*)d_in[0];
    const float* Kin = (const float*)d_in[1];
    const float* Vin = (const float*)d_in[2];
    const float* Wq  = (const float*)d_in[3];
    const float* bq  = (const float*)d_in[4];
    const float* Wk  = (const float*)d_in[5];
    const float* bk  = (const float*)d_in[6];
    const float* Wv  = (const float*)d_in[7];
    const float* bv  = (const float*)d_in[8];
    const float* Wo  = (const float*)d_in[9];
    const float* bo  = (const float*)d_in[10];
    float* out = (float*)d_out;

    unsigned short* p = (unsigned short*)d_ws;
    unsigned short* Wt   = p; p += (size_t)24 * 64 * 512;
    unsigned short* Woth = p; p += (size_t)512 * 512;
    unsigned short* Wotl = p; p += (size_t)512 * 512;
    unsigned short* qbf  = p; p += (size_t)NH * SQ * 64;
    unsigned short* kbf  = p; p += (size_t)NH * SQ * 64;
    unsigned short* vbf  = p; p += (size_t)NH * SQ * 64;
    unsigned short* athi = p; p += (size_t)SQ * DM;
    unsigned short* atlo = p; p += (size_t)SQ * DM;
    float* Opart = (float*)p;                                   // 16 MB
    float* lpart = Opart + (size_t)NSPLIT * NH * SQ * 64;       // 256 KB

    convert_w<<<256, 256, 0, stream>>>(Wq, Wk, Wv, Wo, Wt, Woth, Wotl);
    qkv_mfma<<<dim3(32, 8, 3), 256, 0, stream>>>(emb, Kin, Vin, Wt, bq, bk, bv,
                                                 qbf, kbf, vbf);
    attn_fwd<<<dim3(32, 8, NSPLIT), 256, 0, stream>>>(qbf, kbf, vbf, Opart, lpart);
    attn_combine<<<512, 256, 0, stream>>>(Opart, lpart, athi, atlo);
    out_proj<<<dim3(64, 8), 256, 0, stream>>>(athi, atlo, Woth, Wotl, bo, out);
}